// Round 1
// baseline (431.501 us; speedup 1.0000x reference)
//
#include <hip/hip_runtime.h>

// SRLoss: loss = mean((inp - avgpool10x10(output))^2) + BCE(output, target)
// output/target: [32,1,1280,1280] f32; inp: [32,1,128,128] f32; out: scalar f32.
//
// Memory-bound: 422 MB mandatory read -> ~67 us floor at 6.3 TB/s.
// Fused single pass: each workgroup owns one band (b, pooled_row) = 10x1280,
// reads output+target once (float4 coalesced), BCE in registers, pooled column
// sums in LDS (atomicAdd, <=2 pcols per float4), then 128 MSE terms, block
// reduce, one pre-normalized global atomicAdd into d_out[0].

#define BATCH 32
#define HH 1280
#define WW 1280
#define PH 128
#define PW 128
#define SC 10

static constexpr float EPSV = 1e-20f;
static constexpr float INV_NB = 1.0f / (float)(BATCH * HH * WW);   // bce mean
static constexpr float INV_NM = 1.0f / (float)(BATCH * PH * PW);   // mse mean

__global__ __launch_bounds__(256) void srloss_kernel(
    const float* __restrict__ output,
    const float* __restrict__ target,
    const float* __restrict__ inp,
    float* __restrict__ out)
{
    __shared__ float psum[PW];   // pooled column sums for this band
    __shared__ float red[4];     // cross-wave reduction scratch

    const int t = threadIdx.x;
    const int band = blockIdx.x;         // 0 .. BATCH*PH-1
    const int b = band / PH;
    const int pr = band % PH;

    if (t < PW) psum[t] = 0.0f;
    __syncthreads();

    const size_t base = ((size_t)b * HH + (size_t)pr * SC) * WW;
    const float4* __restrict__ o4p = (const float4*)(output + base);
    const float4* __restrict__ t4p = (const float4*)(target + base);

    float bce_acc = 0.0f;
    const int NV = (SC * WW) / 4;        // 3200 float4 per band
    for (int c = t; c < NV; c += 256) {
        const float4 o4 = o4p[c];
        const float4 t4 = t4p[c];
        float o[4]  = {o4.x, o4.y, o4.z, o4.w};
        float tg[4] = {t4.x, t4.y, t4.z, t4.w};
        float s = 0.0f;
        #pragma unroll
        for (int j = 0; j < 4; ++j) {
            float om  = (o[j] == 0.0f) ? EPSV : o[j];
            float ocr = 1.0f - o[j];
            float oc  = (ocr == 0.0f) ? EPSV : ocr;
            s += tg[j] * __logf(om) + (1.0f - tg[j]) * __logf(oc);
        }
        bce_acc += s;

        // pooled-column accumulation: float4 starts at col0 (col0 % 10 in
        // {0,2,4,6,8}); only r==8 straddles two pooled columns.
        const int col0 = (4 * c) % WW;
        const int p0 = col0 / SC;
        const int r = col0 % SC;
        if (r == 8) {
            atomicAdd(&psum[p0],     o[0] + o[1]);
            atomicAdd(&psum[p0 + 1], o[2] + o[3]);
        } else {
            atomicAdd(&psum[p0], (o[0] + o[1]) + (o[2] + o[3]));
        }
    }
    __syncthreads();

    // MSE terms: one pooled element per thread for t < 128
    float mse_acc = 0.0f;
    if (t < PW) {
        const float pooled = psum[t] * (1.0f / (float)(SC * SC));
        const float iv = inp[(size_t)band * PW + t];
        const float d = iv - pooled;
        mse_acc = d * d;
    }

    // per-block contribution, pre-normalized: loss = -bce_mean_sum + mse_mean_sum
    float contrib = (-INV_NB) * bce_acc + INV_NM * mse_acc;

    #pragma unroll
    for (int off = 32; off > 0; off >>= 1)
        contrib += __shfl_down(contrib, off, 64);
    const int wave = t >> 6;
    if ((t & 63) == 0) red[wave] = contrib;
    __syncthreads();
    if (t == 0) {
        atomicAdd(out, (red[0] + red[1]) + (red[2] + red[3]));
    }
}

extern "C" void kernel_launch(void* const* d_in, const int* in_sizes, int n_in,
                              void* d_out, int out_size, void* d_ws, size_t ws_size,
                              hipStream_t stream) {
    const float* output = (const float*)d_in[0];
    const float* target = (const float*)d_in[1];
    const float* inp    = (const float*)d_in[2];
    float* out = (float*)d_out;

    // d_out is poisoned (0xAA) before every timed replay; zero it ourselves.
    hipMemsetAsync(out, 0, sizeof(float), stream);

    srloss_kernel<<<BATCH * PH, 256, 0, stream>>>(output, target, inp, out);
}

// Round 2
// 413.756 us; speedup vs baseline: 1.0429x; 1.0429x over previous
//
#include <hip/hip_runtime.h>

// SRLoss: loss = mean((inp - avgpool10x10(output))^2) + BCE(output, target)
// output/target: [32,1,1280,1280] f32; inp: [32,1,128,128] f32; out: scalar f32.
//
// R1 post-mortem: 256-thread version compiled to VGPR=16, no unroll ->
// latency-bound (170 us, VALUBusy 30%, HBM 15%). Fix: 640 threads/block,
// exactly 5 float4-pair iterations per thread, fully unrolled loads up front
// (10 outstanding 16B loads/lane). Side win: with stride 640, c mod 320 is
// k-invariant -> each thread's 5 float4s share one pooled-column pair, so
// pooled sums accumulate in registers and LDS atomics leave the loop.

#define BATCH 32
#define HH 1280
#define WW 1280
#define PH 128
#define PW 128
#define SC 10
#define NT 640                      // threads per block (10 waves)
#define NV ((SC * WW) / 4)          // 3200 float4 per band
#define KITER (NV / NT)             // exactly 5

static constexpr float EPSV = 1e-20f;
static constexpr float INV_NB = 1.0f / (float)(BATCH * HH * WW);   // bce mean
static constexpr float INV_NM = 1.0f / (float)(BATCH * PH * PW);   // mse mean

__global__ __launch_bounds__(NT) void srloss_kernel(
    const float* __restrict__ output,
    const float* __restrict__ target,
    const float* __restrict__ inp,
    float* __restrict__ out)
{
    __shared__ float psum[PW];      // pooled column sums for this band
    __shared__ float red[NT / 64];  // cross-wave reduction scratch

    const int t = threadIdx.x;
    const int band = blockIdx.x;    // 0 .. BATCH*PH-1
    const int b = band >> 7;        // band / 128
    const int pr = band & 127;      // band % 128

    if (t < PW) psum[t] = 0.0f;
    __syncthreads();

    const size_t base = ((size_t)b * HH + (size_t)pr * SC) * WW;
    const float4* __restrict__ o4p = (const float4*)(output + base);
    const float4* __restrict__ t4p = (const float4*)(target + base);

    // Issue all 10 loads up front -> deep MLP, BW-bound not latency-bound.
    float4 ov[KITER], tv[KITER];
    #pragma unroll
    for (int k = 0; k < KITER; ++k) ov[k] = o4p[t + NT * k];
    #pragma unroll
    for (int k = 0; k < KITER; ++k) tv[k] = t4p[t + NT * k];

    float bce_acc = 0.0f;
    float s0 = 0.0f, s1 = 0.0f;     // pooled sums: first half / second half of float4
    #pragma unroll
    for (int k = 0; k < KITER; ++k) {
        const float o[4]  = {ov[k].x, ov[k].y, ov[k].z, ov[k].w};
        const float tg[4] = {tv[k].x, tv[k].y, tv[k].z, tv[k].w};
        #pragma unroll
        for (int j = 0; j < 4; ++j) {
            const float om  = (o[j] == 0.0f) ? EPSV : o[j];
            const float ocr = 1.0f - o[j];
            const float oc  = (ocr == 0.0f) ? EPSV : ocr;
            bce_acc += tg[j] * __logf(om) + (1.0f - tg[j]) * __logf(oc);
        }
        s0 += o[0] + o[1];
        s1 += o[2] + o[3];
    }

    // c = t + 640k -> col0 = 4*(t mod 320), identical for all k.
    const int col0 = 4 * (t % 320);
    const int p0 = col0 / SC;       // pooled column of o[0],o[1]
    if ((col0 % SC) == 8) {         // straddle: o[2],o[3] belong to p0+1
        atomicAdd(&psum[p0],     s0);
        atomicAdd(&psum[p0 + 1], s1);
    } else {
        atomicAdd(&psum[p0], s0 + s1);
    }
    __syncthreads();

    // MSE terms: one pooled element per thread for t < 128
    float mse_acc = 0.0f;
    if (t < PW) {
        const float pooled = psum[t] * (1.0f / (float)(SC * SC));
        const float iv = inp[(size_t)band * PW + t];
        const float d = iv - pooled;
        mse_acc = d * d;
    }

    // per-block contribution, pre-normalized
    float contrib = (-INV_NB) * bce_acc + INV_NM * mse_acc;

    #pragma unroll
    for (int off = 32; off > 0; off >>= 1)
        contrib += __shfl_down(contrib, off, 64);
    if ((t & 63) == 0) red[t >> 6] = contrib;
    __syncthreads();
    if (t == 0) {
        float s = 0.0f;
        #pragma unroll
        for (int w = 0; w < NT / 64; ++w) s += red[w];
        atomicAdd(out, s);
    }
}

extern "C" void kernel_launch(void* const* d_in, const int* in_sizes, int n_in,
                              void* d_out, int out_size, void* d_ws, size_t ws_size,
                              hipStream_t stream) {
    const float* output = (const float*)d_in[0];
    const float* target = (const float*)d_in[1];
    const float* inp    = (const float*)d_in[2];
    float* out = (float*)d_out;

    // d_out is poisoned (0xAA) before every timed replay; zero it ourselves.
    hipMemsetAsync(out, 0, sizeof(float), stream);

    srloss_kernel<<<BATCH * PH, NT, 0, stream>>>(output, target, inp, out);
}